// Round 3
// baseline (1560.179 us; speedup 1.0000x reference)
//
#include <hip/hip_runtime.h>
#include <math.h>

#define N_    8
#define C_    256
#define H_    64
#define W_    64
#define HW    4096
#define OUT_  256
#define HEADS 8
#define HD    32
#define K2    9
#define OFFCH 144   // HEADS*K2*2
#define AWCH  72    // HEADS*K2

// ---------------------------------------------------------------------------
// Fused 3x3 conv (pad=1, stride=1) producing offsets (ch 0..143, +bias) and
// attention weights (ch 144..215, +bias, sigmoid). 16x16 spatial tile per
// block, 8 output channels per block, 8-input-channel LDS patch staging.
// Weights are read through uniform (scalar) loads.
// ---------------------------------------------------------------------------
__global__ __launch_bounds__(256) void conv_offattn_kernel(
    const float* __restrict__ x,
    const float* __restrict__ off_w, const float* __restrict__ off_b,
    const float* __restrict__ attn_w, const float* __restrict__ attn_b,
    float* __restrict__ offs, float* __restrict__ aw)
{
  const int n    = blockIdx.z;
  const int ob   = blockIdx.y;          // 0..26 (8 out-channels each)
  const int tile = blockIdx.x;          // 0..15 (4x4 tiles of 16x16)
  const int ty0 = (tile >> 2) << 4;
  const int tx0 = (tile & 3) << 4;
  const int tid = threadIdx.x;
  const int ty = tid >> 4, tx = tid & 15;
  const int oc0 = ob << 3;
  const bool is_attn = (oc0 >= OFFCH);
  const float* __restrict__ wbase = is_attn ? attn_w : off_w;
  const int ocw0 = is_attn ? (oc0 - OFFCH) : oc0;

  __shared__ float patch[8][18][18];

  float acc[8];
#pragma unroll
  for (int i = 0; i < 8; ++i) acc[i] = 0.f;

  for (int c0 = 0; c0 < C_; c0 += 8) {
    // cooperative load of 8 channels' 18x18 halo patch (zero padded)
    for (int i = tid; i < 8 * 324; i += 256) {
      int cl  = i / 324;
      int rem = i - cl * 324;
      int py  = rem / 18;
      int px  = rem - py * 18;
      int gy = ty0 - 1 + py, gx = tx0 - 1 + px;
      float v = 0.f;
      if ((unsigned)gy < (unsigned)H_ && (unsigned)gx < (unsigned)W_)
        v = x[((size_t)(n * C_ + c0 + cl) * H_ + gy) * W_ + gx];
      patch[cl][py][px] = v;
    }
    __syncthreads();
#pragma unroll
    for (int cl = 0; cl < 8; ++cl) {
      float xv[9];
#pragma unroll
      for (int dy = 0; dy < 3; ++dy)
#pragma unroll
        for (int dx = 0; dx < 3; ++dx)
          xv[dy * 3 + dx] = patch[cl][ty + dy][tx + dx];
      const float* wp = wbase + ((size_t)ocw0 * C_ + (c0 + cl)) * 9;
#pragma unroll
      for (int oc = 0; oc < 8; ++oc) {
        const float* w = wp + (size_t)oc * C_ * 9;
#pragma unroll
        for (int k = 0; k < 9; ++k) acc[oc] = fmaf(w[k], xv[k], acc[oc]);
      }
    }
    __syncthreads();
  }

  const int s = (ty0 + ty) * W_ + tx0 + tx;
  if (!is_attn) {
#pragma unroll
    for (int oc = 0; oc < 8; ++oc)
      offs[((size_t)n * OFFCH + oc0 + oc) * HW + s] = acc[oc] + off_b[oc0 + oc];
  } else {
#pragma unroll
    for (int oc = 0; oc < 8; ++oc) {
      float t = acc[oc] + attn_b[ocw0 + oc];
      aw[((size_t)n * AWCH + ocw0 + oc) * HW + s] = 1.f / (1.f + expf(-t));
    }
  }
}

// ---------------------------------------------------------------------------
// v projection: vt[n][s][o] = sum_c Wv[o][c] * x[n][c][s]   (NHWC output)
// 64x64 tile, 256 threads, 4x4 register blocking, K chunks of 16 in LDS.
// ---------------------------------------------------------------------------
__global__ __launch_bounds__(256) void vproj_kernel(
    const float* __restrict__ x, const float* __restrict__ Wv,
    float* __restrict__ vt)
{
  const int n  = blockIdx.z;
  const int o0 = blockIdx.y << 6;
  const int s0 = blockIdx.x << 6;
  const int tid = threadIdx.x;

  __shared__ float As[16][68];  // As[kk][oi] = Wv[(o0+oi)*C + cc+kk]
  __shared__ float Bs[16][64];  // Bs[kk][si] = x[n][(cc+kk)*HW + s0+si]

  const int oi4 = (tid & 15) << 2;
  const int si4 = (tid >> 4) << 2;

  float acc[4][4] = {};

  for (int cc = 0; cc < C_; cc += 16) {
    {
      int kk = tid & 15, oi = tid >> 4;
#pragma unroll
      for (int p = 0; p < 4; ++p)
        As[kk][oi + p * 16] = Wv[(size_t)(o0 + oi + p * 16) * C_ + cc + kk];
    }
    {
      int si = tid & 63, kk0 = tid >> 6;
#pragma unroll
      for (int p = 0; p < 4; ++p)
        Bs[kk0 + p * 4][si] =
            x[((size_t)n * C_ + cc + kk0 + p * 4) * HW + s0 + si];
    }
    __syncthreads();
#pragma unroll
    for (int kk = 0; kk < 16; ++kk) {
      float4 a4 = *(const float4*)&As[kk][oi4];
      float4 b4 = *(const float4*)&Bs[kk][si4];
      float av[4] = {a4.x, a4.y, a4.z, a4.w};
      float bv[4] = {b4.x, b4.y, b4.z, b4.w};
#pragma unroll
      for (int i = 0; i < 4; ++i)
#pragma unroll
        for (int j = 0; j < 4; ++j)
          acc[i][j] = fmaf(av[i], bv[j], acc[i][j]);
    }
    __syncthreads();
  }

#pragma unroll
  for (int j = 0; j < 4; ++j) {
    float4 v4 = make_float4(acc[0][j], acc[1][j], acc[2][j], acc[3][j]);
    *(float4*)&vt[((size_t)n * HW + s0 + si4 + j) * OUT_ + o0 + oi4] = v4;
  }
}

// ---------------------------------------------------------------------------
// Deformable bilinear sampling + K2 weighted sum.
// One thread per (n, head, spatial); v and combined in NHWC.
// ---------------------------------------------------------------------------
__global__ __launch_bounds__(256) void sample_kernel(
    const float* __restrict__ vt, const float* __restrict__ offs,
    const float* __restrict__ aw, float* __restrict__ comb)
{
  const int g = blockIdx.x * 256 + threadIdx.x;  // n*HEADS*HW + h*HW + s
  const int s = g & (HW - 1);
  const int h = (g >> 12) & (HEADS - 1);
  const int n = g >> 15;
  const int yq = s >> 6, xq = s & 63;

  float acc[HD];
#pragma unroll
  for (int j = 0; j < HD; ++j) acc[j] = 0.f;

  const float gxb = -1.f + (2.f / 63.f) * (float)xq;
  const float gyb = -1.f + (2.f / 63.f) * (float)yq;

  for (int k = 0; k < K2; ++k) {
    const int ch = h * K2 + k;
    const float offx = offs[((size_t)n * OFFCH + 2 * ch) * HW + s];
    const float offy = offs[((size_t)n * OFFCH + 2 * ch + 1) * HW + s];
    const float a    = aw[((size_t)n * AWCH + ch) * HW + s];

    const float gx = gxb + offx * (2.f / (float)W_);
    const float gy = gyb + offy * (2.f / (float)H_);
    const float xp = (gx + 1.f) * 0.5f * (float)(W_ - 1);
    const float yp = (gy + 1.f) * 0.5f * (float)(H_ - 1);
    const float fx0 = floorf(xp), fy0 = floorf(yp);
    const int x0 = (int)fx0, y0 = (int)fy0;
    const float wx1 = xp - fx0, wx0 = 1.f - wx1;
    const float wy1 = yp - fy0, wy0 = 1.f - wy1;

#pragma unroll
    for (int cy = 0; cy < 2; ++cy) {
      const int yi = y0 + cy;
      if ((unsigned)yi >= (unsigned)H_) continue;
      const float wy = cy ? wy1 : wy0;
#pragma unroll
      for (int cx = 0; cx < 2; ++cx) {
        const int xi = x0 + cx;
        if ((unsigned)xi >= (unsigned)W_) continue;
        const float cw = a * wy * (cx ? wx1 : wx0);
        const float4* vp =
            (const float4*)&vt[((size_t)n * HW + yi * W_ + xi) * OUT_ + h * HD];
#pragma unroll
        for (int j4 = 0; j4 < HD / 4; ++j4) {
          float4 v4 = vp[j4];
          acc[j4 * 4 + 0] = fmaf(cw, v4.x, acc[j4 * 4 + 0]);
          acc[j4 * 4 + 1] = fmaf(cw, v4.y, acc[j4 * 4 + 1]);
          acc[j4 * 4 + 2] = fmaf(cw, v4.z, acc[j4 * 4 + 2]);
          acc[j4 * 4 + 3] = fmaf(cw, v4.w, acc[j4 * 4 + 3]);
        }
      }
    }
  }

  float4* cp = (float4*)&comb[((size_t)n * HW + s) * OUT_ + h * HD];
#pragma unroll
  for (int j4 = 0; j4 < HD / 4; ++j4)
    cp[j4] = make_float4(acc[j4 * 4 + 0], acc[j4 * 4 + 1], acc[j4 * 4 + 2],
                         acc[j4 * 4 + 3]);
}

// ---------------------------------------------------------------------------
// Output projection: out[n][o][s] = sum_c Wo[o][c] * comb[n][s][c]
// ---------------------------------------------------------------------------
__global__ __launch_bounds__(256) void wo_kernel(
    const float* __restrict__ comb, const float* __restrict__ Wo,
    float* __restrict__ out)
{
  const int n  = blockIdx.z;
  const int o0 = blockIdx.y << 6;
  const int s0 = blockIdx.x << 6;
  const int tid = threadIdx.x;

  __shared__ float As[16][68];  // As[kk][oi] = Wo[(o0+oi)*OUT + cc+kk]
  __shared__ float Bs[16][68];  // Bs[kk][si] = comb[(n*HW+s0+si)*OUT + cc+kk]

  const int oi4 = (tid & 15) << 2;
  const int si4 = (tid >> 4) << 2;

  float acc[4][4] = {};

  for (int cc = 0; cc < OUT_; cc += 16) {
    {
      int kk = tid & 15, oi = tid >> 4;
#pragma unroll
      for (int p = 0; p < 4; ++p)
        As[kk][oi + p * 16] = Wo[(size_t)(o0 + oi + p * 16) * OUT_ + cc + kk];
    }
    {
      int kk = tid & 15, si = tid >> 4;
#pragma unroll
      for (int p = 0; p < 4; ++p)
        Bs[kk][si + p * 16] =
            comb[((size_t)n * HW + s0 + si + p * 16) * OUT_ + cc + kk];
    }
    __syncthreads();
#pragma unroll
    for (int kk = 0; kk < 16; ++kk) {
      float4 a4 = *(const float4*)&As[kk][oi4];
      float4 b4 = *(const float4*)&Bs[kk][si4];
      float av[4] = {a4.x, a4.y, a4.z, a4.w};
      float bv[4] = {b4.x, b4.y, b4.z, b4.w};
#pragma unroll
      for (int i = 0; i < 4; ++i)
#pragma unroll
        for (int j = 0; j < 4; ++j)
          acc[i][j] = fmaf(av[i], bv[j], acc[i][j]);
    }
    __syncthreads();
  }

#pragma unroll
  for (int i = 0; i < 4; ++i) {
    float4 v4 = make_float4(acc[i][0], acc[i][1], acc[i][2], acc[i][3]);
    *(float4*)&out[((size_t)n * OUT_ + o0 + oi4 + i) * HW + s0 + si4] = v4;
  }
}

// ---------------------------------------------------------------------------
extern "C" void kernel_launch(void* const* d_in, const int* in_sizes, int n_in,
                              void* d_out, int out_size, void* d_ws,
                              size_t ws_size, hipStream_t stream)
{
  const float* x      = (const float*)d_in[0];
  // d_in[1] = Wq, d_in[2] = Wk : dead code in the reference (q,k unused)
  const float* Wv     = (const float*)d_in[3];
  const float* off_w  = (const float*)d_in[4];
  const float* off_b  = (const float*)d_in[5];
  const float* attn_w = (const float*)d_in[6];
  const float* attn_b = (const float*)d_in[7];
  const float* Wo     = (const float*)d_in[8];
  float* out = (float*)d_out;

  float* vt   = (float*)d_ws;                       // N*HW*OUT   (33.5 MB)
  float* offs = vt + (size_t)N_ * HW * OUT_;        // N*144*HW   (18.9 MB)
  float* aw   = offs + (size_t)N_ * OFFCH * HW;     // N*72*HW    ( 9.4 MB)
  float* comb = aw + (size_t)N_ * AWCH * HW;        // N*HW*OUT   (33.5 MB)

  conv_offattn_kernel<<<dim3(16, 27, N_), 256, 0, stream>>>(
      x, off_w, off_b, attn_w, attn_b, offs, aw);
  vproj_kernel<<<dim3(HW / 64, OUT_ / 64, N_), 256, 0, stream>>>(x, Wv, vt);
  sample_kernel<<<dim3((N_ * HEADS * HW) / 256), 256, 0, stream>>>(vt, offs,
                                                                   aw, comb);
  wo_kernel<<<dim3(HW / 64, OUT_ / 64, N_), 256, 0, stream>>>(comb, Wo, out);
}

// Round 4
// 370.139 us; speedup vs baseline: 4.2151x; 4.2151x over previous
//
#include <hip/hip_runtime.h>
#include <math.h>

#define N_    8
#define C_    256
#define H_    64
#define W_    64
#define HW    4096
#define OUT_  256
#define HEADS 8
#define HD    32
#define K2    9
#define OFFCH 144   // HEADS*K2*2
#define AWCH  72    // HEADS*K2
#define COP   224   // padded conv output channels (216 used)
#define KTOT  2304  // 9 taps * 256 c

typedef __bf16 bf16x8 __attribute__((ext_vector_type(8)));
typedef float  f32x4  __attribute__((ext_vector_type(4)));

// ---------------------------------------------------------------------------
// pack_x: fp32 NCHW -> bf16 NHWC  (xp[n][y][x][c]), LDS 64x64 tile transpose.
// grid (4 c-tiles, 64 y, 8 n), 256 threads.
// ---------------------------------------------------------------------------
__global__ __launch_bounds__(256) void pack_x_kernel(
    const float* __restrict__ x, __bf16* __restrict__ xp)
{
  const int c0 = blockIdx.x << 6;
  const int y  = blockIdx.y;
  const int n  = blockIdx.z;
  const int tid = threadIdx.x;
  __shared__ float tile[64][65];

  const int tx = tid & 63, tg = tid >> 6;
#pragma unroll
  for (int i = 0; i < 16; ++i) {
    int cl = tg + (i << 2);
    tile[cl][tx] = x[((size_t)(n * C_ + c0 + cl) * H_ + y) * W_ + tx];
  }
  __syncthreads();
#pragma unroll
  for (int i = 0; i < 16; ++i) {
    int xl = tg + (i << 2);
    xp[((size_t)(n * HW) + y * W_ + xl) * C_ + c0 + tx] = (__bf16)tile[tx][xl];
  }
}

// ---------------------------------------------------------------------------
// pack_w: off_w/attn_w (fp32 [co][c][3][3]) -> bf16 Wp[224][tap][c] (tap-major K)
// rows 216..223 zero. Also packs biases (fp32[224], pad 0).
// grid 224 blocks x 256 threads (thread = c).
// ---------------------------------------------------------------------------
__global__ __launch_bounds__(256) void pack_w_kernel(
    const float* __restrict__ off_w, const float* __restrict__ off_b,
    const float* __restrict__ attn_w, const float* __restrict__ attn_b,
    __bf16* __restrict__ Wp, float* __restrict__ biasp)
{
  const int co = blockIdx.x;
  const int c  = threadIdx.x;
  const float* base = nullptr;
  if (co < OFFCH)      base = off_w  + ((size_t)co * C_ + c) * 9;
  else if (co < 216)   base = attn_w + ((size_t)(co - OFFCH) * C_ + c) * 9;
#pragma unroll
  for (int t = 0; t < 9; ++t) {
    float w = base ? base[t] : 0.f;
    Wp[(size_t)co * KTOT + t * C_ + c] = (__bf16)w;
  }
  if (c == 0) {
    float b = 0.f;
    if (co < OFFCH) b = off_b[co];
    else if (co < 216) b = attn_b[co - OFFCH];
    biasp[co] = b;
  }
}

// ---------------------------------------------------------------------------
// conv_mfma: implicit-GEMM 3x3 conv via 16x16x32 bf16 MFMA.
//   P[n][s][co] = sigmoid?( sum_k  A_im2col[s][k] * W[co][k] + bias[co] )
// Block: 128 spatial rows (2 image rows) x 112 co. 4 waves, each 2 Mtiles x 7 Ntiles.
// A staged per 32-c slice (reused over 9 taps); B per (tap, c-slice).
// LDS inner strides padded to 40 bf16 (80 B) -> 16B-aligned, low-conflict.
// grid (32 s-tiles, 2 co-halves, 8 n), 256 threads.
// ---------------------------------------------------------------------------
__global__ __launch_bounds__(256) void conv_mfma_kernel(
    const __bf16* __restrict__ xp, const __bf16* __restrict__ Wp,
    const float* __restrict__ biasp, __bf16* __restrict__ P)
{
  const int st = blockIdx.x;      // s-tile: image rows y0, y0+1
  const int bn = blockIdx.y;      // co half (0: 0..111, 1: 112..223)
  const int n  = blockIdx.z;
  const int y0 = st << 1;
  const int tid = threadIdx.x;

  __shared__ __bf16 Asl[4][66][40];   // y (y0-1..y0+2), x (-1..64), 32 c (pad 40)
  __shared__ __bf16 Bsl[112][40];     // co x 32 k (pad 40)

  const int lw = tid & 63, wv = tid >> 6;
  const int trow = wv >> 1;           // wave's image row (0/1)
  const int xb   = (wv & 1) << 5;     // wave's x base (0/32), 2 Mtiles of 16
  const int lr = lw & 15, lg = lw >> 4;

  f32x4 acc[2][7];
#pragma unroll
  for (int m = 0; m < 2; ++m)
#pragma unroll
    for (int nt = 0; nt < 7; ++nt) acc[m][nt] = (f32x4){0.f, 0.f, 0.f, 0.f};

  for (int c0 = 0; c0 < C_; c0 += 32) {
    __syncthreads();   // previous iteration's A reads done
    // ---- stage A: 4 rows x 64 x x 32 c  (1024 chunks of 8 bf16) ----
#pragma unroll
    for (int it = 0; it < 4; ++it) {
      int i  = tid + (it << 8);
      int cg = i & 3, xx = (i >> 2) & 63, r = i >> 8;
      int y = y0 - 1 + r;
      uint4 val = make_uint4(0u, 0u, 0u, 0u);
      if ((unsigned)y < (unsigned)H_)
        val = *(const uint4*)&xp[(((size_t)n * HW) + y * W_ + xx) * C_ + c0 + (cg << 3)];
      *(uint4*)&Asl[r][xx + 1][cg << 3] = val;
    }
    if (tid < 32) {    // zero halo columns x=-1 and x=64
      int r = tid >> 3, xe = ((tid >> 2) & 1) ? 65 : 0, cg = tid & 3;
      *(uint4*)&Asl[r][xe][cg << 3] = make_uint4(0u, 0u, 0u, 0u);
    }

    for (int t = 0; t < 9; ++t) {
      __syncthreads(); // A ready (t=0) / previous B reads done (t>0)
      // ---- stage B: 112 co x 32 k (448 chunks) ----
#pragma unroll
      for (int it = 0; it < 2; ++it) {
        int j = tid + (it << 8);
        if (j < 448) {
          int cg = j & 3, co = j >> 2;
          *(uint4*)&Bsl[co][cg << 3] =
              *(const uint4*)&Wp[(size_t)(bn * 112 + co) * KTOT + t * C_ + c0 + (cg << 3)];
        }
      }
      __syncthreads(); // B ready

      const int dy = t / 3 - 1, dx = t % 3 - 1;
      const int r  = trow + dy + 1;
      bf16x8 a0 = *(const bf16x8*)&Asl[r][xb + lr + dx + 1][lg << 3];
      bf16x8 a1 = *(const bf16x8*)&Asl[r][xb + 16 + lr + dx + 1][lg << 3];
#pragma unroll
      for (int nt = 0; nt < 7; ++nt) {
        bf16x8 b = *(const bf16x8*)&Bsl[(nt << 4) + lr][lg << 3];
        acc[0][nt] = __builtin_amdgcn_mfma_f32_16x16x32_bf16(a0, b, acc[0][nt], 0, 0, 0);
        acc[1][nt] = __builtin_amdgcn_mfma_f32_16x16x32_bf16(a1, b, acc[1][nt], 0, 0, 0);
      }
    }
  }

  // ---- epilogue: bias (+ sigmoid for co>=144), store bf16 P[n][s][co] ----
  const int yout = y0 + trow;
#pragma unroll
  for (int m = 0; m < 2; ++m) {
#pragma unroll
    for (int nt = 0; nt < 7; ++nt) {
      const int co = bn * 112 + (nt << 4) + lr;
      const float bias = biasp[co];
#pragma unroll
      for (int reg = 0; reg < 4; ++reg) {
        const int xo = xb + (m << 4) + (lg << 2) + reg;
        float v = acc[m][nt][reg] + bias;
        if (co >= OFFCH) v = 1.f / (1.f + expf(-v));
        P[((size_t)n * HW + yout * W_ + xo) * COP + co] = (__bf16)v;
      }
    }
  }
}

// ---------------------------------------------------------------------------
// v projection (unchanged fp32): vt[n][s][o] = sum_c Wv[o][c] * x[n][c][s]
// ---------------------------------------------------------------------------
__global__ __launch_bounds__(256) void vproj_kernel(
    const float* __restrict__ x, const float* __restrict__ Wv,
    float* __restrict__ vt)
{
  const int n  = blockIdx.z;
  const int o0 = blockIdx.y << 6;
  const int s0 = blockIdx.x << 6;
  const int tid = threadIdx.x;

  __shared__ float As[16][68];
  __shared__ float Bs[16][64];

  const int oi4 = (tid & 15) << 2;
  const int si4 = (tid >> 4) << 2;

  float acc[4][4] = {};

  for (int cc = 0; cc < C_; cc += 16) {
    {
      int kk = tid & 15, oi = tid >> 4;
#pragma unroll
      for (int p = 0; p < 4; ++p)
        As[kk][oi + p * 16] = Wv[(size_t)(o0 + oi + p * 16) * C_ + cc + kk];
    }
    {
      int si = tid & 63, kk0 = tid >> 6;
#pragma unroll
      for (int p = 0; p < 4; ++p)
        Bs[kk0 + p * 4][si] =
            x[((size_t)n * C_ + cc + kk0 + p * 4) * HW + s0 + si];
    }
    __syncthreads();
#pragma unroll
    for (int kk = 0; kk < 16; ++kk) {
      float4 a4 = *(const float4*)&As[kk][oi4];
      float4 b4 = *(const float4*)&Bs[kk][si4];
      float av[4] = {a4.x, a4.y, a4.z, a4.w};
      float bv[4] = {b4.x, b4.y, b4.z, b4.w};
#pragma unroll
      for (int i = 0; i < 4; ++i)
#pragma unroll
        for (int j = 0; j < 4; ++j)
          acc[i][j] = fmaf(av[i], bv[j], acc[i][j]);
    }
    __syncthreads();
  }

#pragma unroll
  for (int j = 0; j < 4; ++j) {
    float4 v4 = make_float4(acc[0][j], acc[1][j], acc[2][j], acc[3][j]);
    *(float4*)&vt[((size_t)n * HW + s0 + si4 + j) * OUT_ + o0 + oi4] = v4;
  }
}

// ---------------------------------------------------------------------------
// Deformable sampling; offsets/aw now read from bf16 P[n][s][co].
// ---------------------------------------------------------------------------
__global__ __launch_bounds__(256) void sample_kernel(
    const float* __restrict__ vt, const __bf16* __restrict__ P,
    float* __restrict__ comb)
{
  const int g = blockIdx.x * 256 + threadIdx.x;
  const int s = g & (HW - 1);
  const int h = (g >> 12) & (HEADS - 1);
  const int n = g >> 15;
  const int yq = s >> 6, xq = s & 63;

  float acc[HD];
#pragma unroll
  for (int j = 0; j < HD; ++j) acc[j] = 0.f;

  const float gxb = -1.f + (2.f / 63.f) * (float)xq;
  const float gyb = -1.f + (2.f / 63.f) * (float)yq;

  const __bf16* prow = P + ((size_t)n * HW + s) * COP;

  for (int k = 0; k < K2; ++k) {
    const float offx = (float)prow[18 * h + 2 * k];
    const float offy = (float)prow[18 * h + 2 * k + 1];
    const float a    = (float)prow[OFFCH + 9 * h + k];

    const float gx = gxb + offx * (2.f / (float)W_);
    const float gy = gyb + offy * (2.f / (float)H_);
    const float xp_ = (gx + 1.f) * 0.5f * (float)(W_ - 1);
    const float yp_ = (gy + 1.f) * 0.5f * (float)(H_ - 1);
    const float fx0 = floorf(xp_), fy0 = floorf(yp_);
    const int x0 = (int)fx0, y0 = (int)fy0;
    const float wx1 = xp_ - fx0, wx0 = 1.f - wx1;
    const float wy1 = yp_ - fy0, wy0 = 1.f - wy1;

#pragma unroll
    for (int cy = 0; cy < 2; ++cy) {
      const int yi = y0 + cy;
      if ((unsigned)yi >= (unsigned)H_) continue;
      const float wy = cy ? wy1 : wy0;
#pragma unroll
      for (int cx = 0; cx < 2; ++cx) {
        const int xi = x0 + cx;
        if ((unsigned)xi >= (unsigned)W_) continue;
        const float cw = a * wy * (cx ? wx1 : wx0);
        const float4* vp =
            (const float4*)&vt[((size_t)n * HW + yi * W_ + xi) * OUT_ + h * HD];
#pragma unroll
        for (int j4 = 0; j4 < HD / 4; ++j4) {
          float4 v4 = vp[j4];
          acc[j4 * 4 + 0] = fmaf(cw, v4.x, acc[j4 * 4 + 0]);
          acc[j4 * 4 + 1] = fmaf(cw, v4.y, acc[j4 * 4 + 1]);
          acc[j4 * 4 + 2] = fmaf(cw, v4.z, acc[j4 * 4 + 2]);
          acc[j4 * 4 + 3] = fmaf(cw, v4.w, acc[j4 * 4 + 3]);
        }
      }
    }
  }

  float4* cp = (float4*)&comb[((size_t)n * HW + s) * OUT_ + h * HD];
#pragma unroll
  for (int j4 = 0; j4 < HD / 4; ++j4)
    cp[j4] = make_float4(acc[j4 * 4 + 0], acc[j4 * 4 + 1], acc[j4 * 4 + 2],
                         acc[j4 * 4 + 3]);
}

// ---------------------------------------------------------------------------
// Output projection (unchanged fp32)
// ---------------------------------------------------------------------------
__global__ __launch_bounds__(256) void wo_kernel(
    const float* __restrict__ comb, const float* __restrict__ Wo,
    float* __restrict__ out)
{
  const int n  = blockIdx.z;
  const int o0 = blockIdx.y << 6;
  const int s0 = blockIdx.x << 6;
  const int tid = threadIdx.x;

  __shared__ float As[16][68];
  __shared__ float Bs[16][68];

  const int oi4 = (tid & 15) << 2;
  const int si4 = (tid >> 4) << 2;

  float acc[4][4] = {};

  for (int cc = 0; cc < OUT_; cc += 16) {
    {
      int kk = tid & 15, oi = tid >> 4;
#pragma unroll
      for (int p = 0; p < 4; ++p)
        As[kk][oi + p * 16] = Wo[(size_t)(o0 + oi + p * 16) * OUT_ + cc + kk];
    }
    {
      int kk = tid & 15, si = tid >> 4;
#pragma unroll
      for (int p = 0; p < 4; ++p)
        Bs[kk][si + p * 16] =
            comb[((size_t)n * HW + s0 + si + p * 16) * OUT_ + cc + kk];
    }
    __syncthreads();
#pragma unroll
    for (int kk = 0; kk < 16; ++kk) {
      float4 a4 = *(const float4*)&As[kk][oi4];
      float4 b4 = *(const float4*)&Bs[kk][si4];
      float av[4] = {a4.x, a4.y, a4.z, a4.w};
      float bv[4] = {b4.x, b4.y, b4.z, b4.w};
#pragma unroll
      for (int i = 0; i < 4; ++i)
#pragma unroll
        for (int j = 0; j < 4; ++j)
          acc[i][j] = fmaf(av[i], bv[j], acc[i][j]);
    }
    __syncthreads();
  }

#pragma unroll
  for (int i = 0; i < 4; ++i) {
    float4 v4 = make_float4(acc[i][0], acc[i][1], acc[i][2], acc[i][3]);
    *(float4*)&out[((size_t)n * OUT_ + o0 + oi4 + i) * HW + s0 + si4] = v4;
  }
}

// ---------------------------------------------------------------------------
extern "C" void kernel_launch(void* const* d_in, const int* in_sizes, int n_in,
                              void* d_out, int out_size, void* d_ws,
                              size_t ws_size, hipStream_t stream)
{
  const float* x      = (const float*)d_in[0];
  // d_in[1] = Wq, d_in[2] = Wk : dead code in the reference (q,k unused)
  const float* Wv     = (const float*)d_in[3];
  const float* off_w  = (const float*)d_in[4];
  const float* off_b  = (const float*)d_in[5];
  const float* attn_w = (const float*)d_in[6];
  const float* attn_b = (const float*)d_in[7];
  const float* Wo     = (const float*)d_in[8];
  float* out = (float*)d_out;

  // workspace layout (xp aliases comb: disjoint lifetimes pack/conv vs sample/wo)
  float*  vt    = (float*)d_ws;                          // 33.55 MB
  float*  comb  = vt + (size_t)N_ * HW * OUT_;           // 33.55 MB
  __bf16* xp    = (__bf16*)comb;                         // 16.78 MB (alias)
  __bf16* P     = (__bf16*)(comb + (size_t)N_ * HW * OUT_);  // 14.68 MB
  __bf16* Wp    = P + (size_t)N_ * HW * COP;             // 1.03 MB
  float*  biasp = (float*)(Wp + (size_t)COP * KTOT);     // 896 B

  pack_w_kernel<<<dim3(COP), 256, 0, stream>>>(off_w, off_b, attn_w, attn_b,
                                               Wp, biasp);
  pack_x_kernel<<<dim3(4, 64, N_), 256, 0, stream>>>(x, xp);
  conv_mfma_kernel<<<dim3(32, 2, N_), 256, 0, stream>>>(xp, Wp, biasp, P);
  vproj_kernel<<<dim3(HW / 64, OUT_ / 64, N_), 256, 0, stream>>>(x, Wv, vt);
  sample_kernel<<<dim3((N_ * HEADS * HW) / 256), 256, 0, stream>>>(vt, P, comb);
  wo_kernel<<<dim3(HW / 64, OUT_ / 64, N_), 256, 0, stream>>>(comb, Wo, out);
}

// Round 7
// 185.582 us; speedup vs baseline: 8.4070x; 1.9945x over previous
//
#include <hip/hip_runtime.h>
#include <math.h>

#define N_    8
#define C_    256
#define H_    64
#define W_    64
#define HW    4096
#define OUT_  256
#define HEADS 8
#define HD    32
#define K2    9
#define OFFCH 144   // HEADS*K2*2
#define AWCH  72    // HEADS*K2
#define COP   224   // padded conv output channels (216 used)
#define KTOT  2304  // 9 taps * 256 c

typedef __bf16 bf16x8 __attribute__((ext_vector_type(8)));
typedef __bf16 bf16x4 __attribute__((ext_vector_type(4)));
typedef float  f32x4  __attribute__((ext_vector_type(4)));

// ---------------------------------------------------------------------------
// pack_x: fp32 NCHW -> bf16 NHWC  (xp[n][y][x][c]), LDS 64x64 tile transpose.
// ---------------------------------------------------------------------------
__global__ __launch_bounds__(256) void pack_x_kernel(
    const float* __restrict__ x, __bf16* __restrict__ xp)
{
  const int c0 = blockIdx.x << 6;
  const int y  = blockIdx.y;
  const int n  = blockIdx.z;
  const int tid = threadIdx.x;
  __shared__ float tile[64][65];

  const int tx = tid & 63, tg = tid >> 6;
#pragma unroll
  for (int i = 0; i < 16; ++i) {
    int cl = tg + (i << 2);
    tile[cl][tx] = x[((size_t)(n * C_ + c0 + cl) * H_ + y) * W_ + tx];
  }
  __syncthreads();
#pragma unroll
  for (int i = 0; i < 16; ++i) {
    int xl = tg + (i << 2);
    xp[((size_t)(n * HW) + y * W_ + xl) * C_ + c0 + tx] = (__bf16)tile[tx][xl];
  }
}

// ---------------------------------------------------------------------------
// pack_w: conv weights -> bf16 Wp[224][tap][c] (tap-major K), + bias pack.
// ---------------------------------------------------------------------------
__global__ __launch_bounds__(256) void pack_w_kernel(
    const float* __restrict__ off_w, const float* __restrict__ off_b,
    const float* __restrict__ attn_w, const float* __restrict__ attn_b,
    __bf16* __restrict__ Wp, float* __restrict__ biasp)
{
  const int co = blockIdx.x;
  const int c  = threadIdx.x;
  const float* base = nullptr;
  if (co < OFFCH)      base = off_w  + ((size_t)co * C_ + c) * 9;
  else if (co < 216)   base = attn_w + ((size_t)(co - OFFCH) * C_ + c) * 9;
#pragma unroll
  for (int t = 0; t < 9; ++t) {
    float w = base ? base[t] : 0.f;
    Wp[(size_t)co * KTOT + t * C_ + c] = (__bf16)w;
  }
  if (c == 0) {
    float b = 0.f;
    if (co < OFFCH) b = off_b[co];
    else if (co < 216) b = attn_b[co - OFFCH];
    biasp[co] = b;
  }
}

// 256x256 fp32 -> bf16 row-major
__global__ __launch_bounds__(256) void pack_mat_kernel(
    const float* __restrict__ Wsrc, __bf16* __restrict__ Wdst)
{
  const int i = blockIdx.x * 256 + threadIdx.x;
  Wdst[i] = (__bf16)Wsrc[i];
}

// ---------------------------------------------------------------------------
// conv_mfma: implicit-GEMM 3x3 conv via 16x16x32 bf16 MFMA.
// ---------------------------------------------------------------------------
__global__ __launch_bounds__(256) void conv_mfma_kernel(
    const __bf16* __restrict__ xp, const __bf16* __restrict__ Wp,
    const float* __restrict__ biasp, __bf16* __restrict__ P)
{
  const int st = blockIdx.x;
  const int bn = blockIdx.y;
  const int n  = blockIdx.z;
  const int y0 = st << 1;
  const int tid = threadIdx.x;

  __shared__ __bf16 Asl[4][66][40];
  __shared__ __bf16 Bsl[112][40];

  const int lw = tid & 63, wv = tid >> 6;
  const int trow = wv >> 1;
  const int xb   = (wv & 1) << 5;
  const int lr = lw & 15, lg = lw >> 4;

  f32x4 acc[2][7];
#pragma unroll
  for (int m = 0; m < 2; ++m)
#pragma unroll
    for (int nt = 0; nt < 7; ++nt) acc[m][nt] = (f32x4){0.f, 0.f, 0.f, 0.f};

  for (int c0 = 0; c0 < C_; c0 += 32) {
    __syncthreads();
#pragma unroll
    for (int it = 0; it < 4; ++it) {
      int i  = tid + (it << 8);
      int cg = i & 3, xx = (i >> 2) & 63, r = i >> 8;
      int y = y0 - 1 + r;
      uint4 val = make_uint4(0u, 0u, 0u, 0u);
      if ((unsigned)y < (unsigned)H_)
        val = *(const uint4*)&xp[(((size_t)n * HW) + y * W_ + xx) * C_ + c0 + (cg << 3)];
      *(uint4*)&Asl[r][xx + 1][cg << 3] = val;
    }
    if (tid < 32) {
      int r = tid >> 3, xe = ((tid >> 2) & 1) ? 65 : 0, cg = tid & 3;
      *(uint4*)&Asl[r][xe][cg << 3] = make_uint4(0u, 0u, 0u, 0u);
    }

    for (int t = 0; t < 9; ++t) {
      __syncthreads();
#pragma unroll
      for (int it = 0; it < 2; ++it) {
        int j = tid + (it << 8);
        if (j < 448) {
          int cg = j & 3, co = j >> 2;
          *(uint4*)&Bsl[co][cg << 3] =
              *(const uint4*)&Wp[(size_t)(bn * 112 + co) * KTOT + t * C_ + c0 + (cg << 3)];
        }
      }
      __syncthreads();

      const int dy = t / 3 - 1, dx = t % 3 - 1;
      const int r  = trow + dy + 1;
      bf16x8 a0 = *(const bf16x8*)&Asl[r][xb + lr + dx + 1][lg << 3];
      bf16x8 a1 = *(const bf16x8*)&Asl[r][xb + 16 + lr + dx + 1][lg << 3];
#pragma unroll
      for (int nt = 0; nt < 7; ++nt) {
        bf16x8 b = *(const bf16x8*)&Bsl[(nt << 4) + lr][lg << 3];
        acc[0][nt] = __builtin_amdgcn_mfma_f32_16x16x32_bf16(a0, b, acc[0][nt], 0, 0, 0);
        acc[1][nt] = __builtin_amdgcn_mfma_f32_16x16x32_bf16(a1, b, acc[1][nt], 0, 0, 0);
      }
    }
  }

  const int yout = y0 + trow;
#pragma unroll
  for (int m = 0; m < 2; ++m) {
#pragma unroll
    for (int nt = 0; nt < 7; ++nt) {
      const int co = bn * 112 + (nt << 4) + lr;
      const float bias = biasp[co];
#pragma unroll
      for (int reg = 0; reg < 4; ++reg) {
        const int xo = xb + (m << 4) + (lg << 2) + reg;
        float v = acc[m][nt][reg] + bias;
        if (co >= OFFCH) v = 1.f / (1.f + expf(-v));
        P[((size_t)n * HW + yout * W_ + xo) * COP + co] = (__bf16)v;
      }
    }
  }
}

// ---------------------------------------------------------------------------
// gemm256: D[n][s][co] (or transposed store) = sum_c A[n][s][c]*Wb[co][c]
// Block: 128 spatial x 128 co, 4 waves (wave = 32 spatial x 128 co).
// MODE 0: store bf16 NHWC (vproj -> vtb). MODE 1: store fp32 NCHW (wo -> out).
// ---------------------------------------------------------------------------
template <int MODE>
__global__ __launch_bounds__(256) void gemm256_kernel(
    const __bf16* __restrict__ A, const __bf16* __restrict__ Wb,
    __bf16* __restrict__ out_b, float* __restrict__ out_f)
{
  const int st = blockIdx.x;      // 32 tiles of 128 spatial
  const int bn = blockIdx.y;      // 2 halves of 128 co
  const int n  = blockIdx.z;
  const int s0 = st << 7;
  const int tid = threadIdx.x;

  __shared__ __bf16 Asl[128][40];
  __shared__ __bf16 Bsl[128][40];

  const int lw = tid & 63, wv = tid >> 6;
  const int lr = lw & 15, lg = lw >> 4;
  const int sm_base = wv << 5;

  f32x4 acc[2][8];
#pragma unroll
  for (int m = 0; m < 2; ++m)
#pragma unroll
    for (int nt = 0; nt < 8; ++nt) acc[m][nt] = (f32x4){0.f, 0.f, 0.f, 0.f};

  for (int c0 = 0; c0 < 256; c0 += 32) {
    __syncthreads();
#pragma unroll
    for (int it = 0; it < 2; ++it) {
      int i = tid + (it << 8);
      int cg = i & 3, r = i >> 2;
      *(uint4*)&Asl[r][cg << 3] =
          *(const uint4*)&A[((size_t)n * HW + s0 + r) * 256 + c0 + (cg << 3)];
    }
#pragma unroll
    for (int it = 0; it < 2; ++it) {
      int i = tid + (it << 8);
      int cg = i & 3, r = i >> 2;
      *(uint4*)&Bsl[r][cg << 3] =
          *(const uint4*)&Wb[(size_t)((bn << 7) + r) * 256 + c0 + (cg << 3)];
    }
    __syncthreads();

    bf16x8 a0 = *(const bf16x8*)&Asl[sm_base + lr][lg << 3];
    bf16x8 a1 = *(const bf16x8*)&Asl[sm_base + 16 + lr][lg << 3];
#pragma unroll
    for (int nt = 0; nt < 8; ++nt) {
      bf16x8 b = *(const bf16x8*)&Bsl[(nt << 4) + lr][lg << 3];
      acc[0][nt] = __builtin_amdgcn_mfma_f32_16x16x32_bf16(a0, b, acc[0][nt], 0, 0, 0);
      acc[1][nt] = __builtin_amdgcn_mfma_f32_16x16x32_bf16(a1, b, acc[1][nt], 0, 0, 0);
    }
  }

#pragma unroll
  for (int m = 0; m < 2; ++m) {
#pragma unroll
    for (int nt = 0; nt < 8; ++nt) {
      const int co = (bn << 7) + (nt << 4) + lr;
      if (MODE == 0) {
#pragma unroll
        for (int reg = 0; reg < 4; ++reg) {
          const int sm = sm_base + (m << 4) + (lg << 2) + reg;
          out_b[((size_t)n * HW + s0 + sm) * 256 + co] = (__bf16)acc[m][nt][reg];
        }
      } else {
        const int sm = sm_base + (m << 4) + (lg << 2);
        float4 v4 = make_float4(acc[m][nt][0], acc[m][nt][1],
                                acc[m][nt][2], acc[m][nt][3]);
        *(float4*)&out_f[((size_t)(n * 256 + co)) * HW + s0 + sm] = v4;
      }
    }
  }
}

// ---------------------------------------------------------------------------
// Deformable sampling, channel-split: 8 lanes per (n,h,s), each owns 4 ch.
// vtb bf16 NHWC; writes comb bf16 NHWC.
// ---------------------------------------------------------------------------
__global__ __launch_bounds__(256) void sample_kernel(
    const __bf16* __restrict__ vtb, const __bf16* __restrict__ P,
    __bf16* __restrict__ comb)
{
  const int gid = blockIdx.x * 256 + threadIdx.x;
  const int cg  = gid & 7;        // channel quad within head
  const int q   = gid >> 3;       // point index
  const int s = q & (HW - 1);
  const int h = (q >> 12) & (HEADS - 1);
  const int n = q >> 15;
  const int yq = s >> 6, xq = s & 63;

  float a0 = 0.f, a1 = 0.f, a2 = 0.f, a3 = 0.f;

  const __bf16* prow  = P + ((size_t)n * HW + s) * COP;
  const __bf16* vbase = vtb + ((size_t)n * HW) * OUT_ + h * HD + (cg << 2);

#pragma unroll
  for (int k = 0; k < K2; ++k) {
    const float offx = (float)prow[18 * h + 2 * k];
    const float offy = (float)prow[18 * h + 2 * k + 1];
    const float a    = (float)prow[OFFCH + 9 * h + k];

    // xp = xq + offx*63/64 (algebraic simplification of the grid math)
    const float xpf = (float)xq + offx * (63.f / 64.f);
    const float ypf = (float)yq + offy * (63.f / 64.f);
    const float fx0 = floorf(xpf), fy0 = floorf(ypf);
    const int x0 = (int)fx0, y0 = (int)fy0;
    const float wx1 = xpf - fx0, wx0 = 1.f - wx1;
    const float wy1 = ypf - fy0, wy0 = 1.f - wy1;

#pragma unroll
    for (int cy = 0; cy < 2; ++cy) {
      const int yi = y0 + cy;
      if ((unsigned)yi >= (unsigned)H_) continue;
      const float wy = cy ? wy1 : wy0;
#pragma unroll
      for (int cx = 0; cx < 2; ++cx) {
        const int xi = x0 + cx;
        if ((unsigned)xi >= (unsigned)W_) continue;
        const float cw = a * wy * (cx ? wx1 : wx0);
        bf16x4 v = *(const bf16x4*)(vbase + (size_t)(yi * W_ + xi) * OUT_);
        a0 = fmaf(cw, (float)v[0], a0);
        a1 = fmaf(cw, (float)v[1], a1);
        a2 = fmaf(cw, (float)v[2], a2);
        a3 = fmaf(cw, (float)v[3], a3);
      }
    }
  }

  bf16x4 r;
  r[0] = (__bf16)a0; r[1] = (__bf16)a1; r[2] = (__bf16)a2; r[3] = (__bf16)a3;
  *(bf16x4*)&comb[((size_t)n * HW + s) * OUT_ + h * HD + (cg << 2)] = r;
}

// ---------------------------------------------------------------------------
extern "C" void kernel_launch(void* const* d_in, const int* in_sizes, int n_in,
                              void* d_out, int out_size, void* d_ws,
                              size_t ws_size, hipStream_t stream)
{
  const float* x      = (const float*)d_in[0];
  // d_in[1] = Wq, d_in[2] = Wk : dead code (q,k unused in reference)
  const float* Wv     = (const float*)d_in[3];
  const float* off_w  = (const float*)d_in[4];
  const float* off_b  = (const float*)d_in[5];
  const float* attn_w = (const float*)d_in[6];
  const float* attn_b = (const float*)d_in[7];
  const float* Wo     = (const float*)d_in[8];
  float* out = (float*)d_out;

  // workspace (all bf16 first, fp32 bias last; ~66 MB total)
  __bf16* vtb   = (__bf16*)d_ws;                         // 16.78 MB
  __bf16* xp    = vtb + (size_t)N_ * HW * OUT_;          // 16.78 MB
  __bf16* comb  = xp + (size_t)N_ * HW * C_;             // 16.78 MB
  __bf16* P     = comb + (size_t)N_ * HW * OUT_;         // 14.68 MB
  __bf16* Wp    = P + (size_t)N_ * HW * COP;             //  1.03 MB
  __bf16* Wvb   = Wp + (size_t)COP * KTOT;               //  128 KB
  __bf16* Wob   = Wvb + (size_t)OUT_ * C_;               //  128 KB
  float*  biasp = (float*)(Wob + (size_t)OUT_ * OUT_);   //  896 B

  pack_w_kernel<<<dim3(COP), 256, 0, stream>>>(off_w, off_b, attn_w, attn_b,
                                               Wp, biasp);
  pack_mat_kernel<<<dim3(256), 256, 0, stream>>>(Wv, Wvb);
  pack_mat_kernel<<<dim3(256), 256, 0, stream>>>(Wo, Wob);
  pack_x_kernel<<<dim3(4, 64, N_), 256, 0, stream>>>(x, xp);
  conv_mfma_kernel<<<dim3(32, 2, N_), 256, 0, stream>>>(xp, Wp, biasp, P);
  gemm256_kernel<0><<<dim3(32, 2, N_), 256, 0, stream>>>(xp, Wvb, vtb, nullptr);
  sample_kernel<<<dim3((N_ * HEADS * HW * 8) / 256), 256, 0, stream>>>(vtb, P,
                                                                       comb);
  gemm256_kernel<1><<<dim3(32, 2, N_), 256, 0, stream>>>(comb, Wob, nullptr,
                                                         out);
}